// Round 3
// baseline (119.067 us; speedup 1.0000x reference)
//
#include <hip/hip_runtime.h>

// Problem constants
#define BATCH 8
#define HW_N  1024   // 32*32
#define CD    128    // channels
#define W_IMG 32
#define CH_O  30
#define F_N   900    // 30*30

// Workspace layout (bytes)
#define OFF_QH  0u
#define OFF_QL  2097152u
#define OFF_KH  4194304u
#define OFF_KL  6291456u
#define OFF_V   8388608u
#define OFF_D   8421376u    // 8192*25*4 = 819200
#define OFF_TP  9240576u    // 8192*8 doubles = 524288
#define OFF_TVP 9764864u    // 524288 -> ends 10289152

typedef __bf16 bf16x8 __attribute__((ext_vector_type(8)));
typedef float  f32x4  __attribute__((ext_vector_type(4)));

// MFMA-fragment-order global layout for Q/K splits:
// off(R,c) = (R>>4)*2048 + [ (c>>5)*4 + ((c>>3)&3) ]*128 + (R&15)*8 + (c&7)
// i.e. [rtile(16 rows)][kc(4 of 32ch)][q(4)][i(16)][j(8)] -- A and B frags
// read as contiguous 16B at (q,i); staging into LDS is identity/contiguous.
__device__ __forceinline__ size_t frag_off(int R, int c) {
    return (size_t)(R >> 4) * 2048 +
           (size_t)((((c >> 5) * 4 + ((c >> 3) & 3)) * 128) + ((R & 15) * 8) + (c & 7));
}

__device__ __forceinline__ void async16(const __bf16* g, __bf16* l) {
    __builtin_amdgcn_global_load_lds(
        (const __attribute__((address_space(1))) unsigned int*)g,
        (__attribute__((address_space(3))) unsigned int*)l,
        16, 0, 0);
}

// -------------------------------------------------------------------------
// Kernel A: Q = xf@Wq^T + bq ; K = xf@Wk^T + bk ; V = xf@wv + bv
// Emits bf16 split pairs in fragment-order layout. 256 blocks x 256 thr.
// -------------------------------------------------------------------------
__global__ __launch_bounds__(256) void qkv_kernel(
    const float* __restrict__ xf,
    const float* __restrict__ Wq, const float* __restrict__ bq,
    const float* __restrict__ Wk, const float* __restrict__ bk,
    const float* __restrict__ wv, const float* __restrict__ bv,
    __bf16* __restrict__ Qh, __bf16* __restrict__ Ql,
    __bf16* __restrict__ Kh, __bf16* __restrict__ Kl,
    float* __restrict__ V)
{
    __shared__ float xs[32][132];
    __shared__ float wqs[32][132];
    __shared__ float wks[32][132];
    const int t = threadIdx.x;
    const int rowbase = blockIdx.x * 32;

#pragma unroll
    for (int m = 0; m < 4; ++m) {
        int id = t + 256 * m;
        int r  = id >> 5;
        int kq = id & 31;
        *(float4*)&xs[r][kq * 4] =
            *(const float4*)&xf[(size_t)(rowbase + r) * CD + kq * 4];
    }

    const int tx = t & 15, ty = t >> 4;

    for (int cc = 0; cc < 4; ++cc) {
        __syncthreads();
#pragma unroll
        for (int m = 0; m < 4; ++m) {
            int id = t + 256 * m;
            int r  = id >> 5;
            int kq = id & 31;
            *(float4*)&wqs[r][kq * 4] =
                *(const float4*)&Wq[(size_t)(cc * 32 + r) * CD + kq * 4];
            *(float4*)&wks[r][kq * 4] =
                *(const float4*)&Wk[(size_t)(cc * 32 + r) * CD + kq * 4];
        }
        __syncthreads();

        float aq[2][2], ak[2][2];
#pragma unroll
        for (int j = 0; j < 2; ++j)
#pragma unroll
            for (int m = 0; m < 2; ++m) { aq[j][m] = 0.f; ak[j][m] = 0.f; }

#pragma unroll 8
        for (int k = 0; k < CD; k += 4) {
            float4 x[2], q[2], kk[2];
            x[0]  = *(const float4*)&xs[ty][k];
            x[1]  = *(const float4*)&xs[ty + 16][k];
            q[0]  = *(const float4*)&wqs[tx][k];
            q[1]  = *(const float4*)&wqs[tx + 16][k];
            kk[0] = *(const float4*)&wks[tx][k];
            kk[1] = *(const float4*)&wks[tx + 16][k];
#pragma unroll
            for (int j = 0; j < 2; ++j)
#pragma unroll
                for (int m = 0; m < 2; ++m) {
                    aq[j][m] += x[j].x * q[m].x + x[j].y * q[m].y +
                                x[j].z * q[m].z + x[j].w * q[m].w;
                    ak[j][m] += x[j].x * kk[m].x + x[j].y * kk[m].y +
                                x[j].z * kk[m].z + x[j].w * kk[m].w;
                }
        }

#pragma unroll
        for (int j = 0; j < 2; ++j)
#pragma unroll
            for (int m = 0; m < 2; ++m) {
                int r = ty + 16 * j;
                int c = cc * 32 + tx + 16 * m;
                int R = rowbase + r;
                size_t o = frag_off(R, c);
                float qv = aq[j][m] + bq[c];
                float kv = ak[j][m] + bk[c];
                __bf16 qh = (__bf16)qv;
                __bf16 ql = (__bf16)(qv - (float)qh);
                __bf16 kh2 = (__bf16)kv;
                __bf16 kl2 = (__bf16)(kv - (float)kh2);
                Qh[o] = qh;  Ql[o] = ql;
                Kh[o] = kh2; Kl[o] = kl2;
            }
    }

    __syncthreads();
    if (t < 32) {
        float s = 0.f;
#pragma unroll 8
        for (int k = 0; k < CD; ++k) s += xs[t][k] * wv[k];
        V[rowbase + t] = s + bv[0];
    }
}

// -------------------------------------------------------------------------
// Kernel B: S = Q@K^T (bf16 MFMA, 3-term split), fused exp/rowsums/band.
// grid (8,8,8): batch x 128-rowblock x 128-colblock; 256 thr = 4 waves 2x2.
// global_load_lds(16B) staging into fragment-order LDS; no atomics:
// per-colblock double partials Tp/TVp.
// -------------------------------------------------------------------------
#define A_H 0
#define A_L 16384
#define B_H 32768
#define B_L 49152
#define VS_OFF 65536
#define ATTN_LDS_TOTAL 66048
#define SCR2 16896

__global__ __launch_bounds__(256, 2) void attn_kernel(
    const __bf16* __restrict__ Qh, const __bf16* __restrict__ Ql,
    const __bf16* __restrict__ Kh, const __bf16* __restrict__ Kl,
    const float* __restrict__ V,
    double* __restrict__ Tp, double* __restrict__ TVp,
    float* __restrict__ D)
{
    extern __shared__ char lds[];
    __bf16* Ah = (__bf16*)(lds + A_H);
    __bf16* Al = (__bf16*)(lds + A_L);
    __bf16* Bh = (__bf16*)(lds + B_H);
    __bf16* Bl = (__bf16*)(lds + B_L);
    float*  Vs = (float*)(lds + VS_OFF);

    const int b  = blockIdx.x;
    const int rb = blockIdx.y;
    const int cb = blockIdx.z;
    const int t  = threadIdx.x;
    const int w    = t >> 6;
    const int lane = t & 63;
    const int q    = lane >> 4;
    const int i    = lane & 15;
    const int wy = w >> 1, wx = w & 1;

    if (t < 128) Vs[t] = V[b * HW_N + cb * 128 + t];

    f32x4 acc[4][4];
#pragma unroll
    for (int r = 0; r < 4; ++r)
#pragma unroll
        for (int f = 0; f < 4; ++f) acc[r][f] = (f32x4){0.f, 0.f, 0.f, 0.f};

    const size_t abase = (size_t)(b * 8 + rb) * 16384;   // bf16 units
    const size_t bbase = (size_t)(b * 8 + cb) * 16384;

    for (int kh = 0; kh < 2; ++kh) {
        __syncthreads();
#pragma unroll
        for (int m = 0; m < 4; ++m) {
            int id = t + 256 * m;                    // 0..1023, 16B chunks
            size_t goff = (size_t)(id >> 7) * 2048 + kh * 1024 + (id & 127) * 8;
            int loff = id * 8;                       // identity LDS layout
            async16(Qh + abase + goff, Ah + loff);
            async16(Ql + abase + goff, Al + loff);
            async16(Kh + bbase + goff, Bh + loff);
            async16(Kl + bbase + goff, Bl + loff);
        }
        asm volatile("s_waitcnt vmcnt(0)" ::: "memory");
        __syncthreads();

#pragma unroll
        for (int kcl = 0; kcl < 2; ++kcl) {
            bf16x8 ah[4], al4[4], bh4[4], bl4[4];
#pragma unroll
            for (int r = 0; r < 4; ++r) {
                int ao = (((wy * 4 + r) * 2 + kcl) * 4 + q) * 128 + i * 8;
                ah[r]  = *(bf16x8*)&Ah[ao];
                al4[r] = *(bf16x8*)&Al[ao];
                int bo = (((wx * 4 + r) * 2 + kcl) * 4 + q) * 128 + i * 8;
                bh4[r] = *(bf16x8*)&Bh[bo];
                bl4[r] = *(bf16x8*)&Bl[bo];
            }
#pragma unroll
            for (int r = 0; r < 4; ++r)
#pragma unroll
                for (int f = 0; f < 4; ++f) {
                    acc[r][f] = __builtin_amdgcn_mfma_f32_16x16x32_bf16(
                        ah[r], bh4[f], acc[r][f], 0, 0, 0);
                    acc[r][f] = __builtin_amdgcn_mfma_f32_16x16x32_bf16(
                        ah[r], bl4[f], acc[r][f], 0, 0, 0);
                    acc[r][f] = __builtin_amdgcn_mfma_f32_16x16x32_bf16(
                        al4[r], bh4[f], acc[r][f], 0, 0, 0);
                }
        }
    }

    // ---- epilogue: exp, partial row sums, banded D store ----
    float st[4][4], stv[4][4];
#pragma unroll
    for (int r = 0; r < 4; ++r)
#pragma unroll
        for (int g = 0; g < 4; ++g) { st[r][g] = 0.f; stv[r][g] = 0.f; }

    const bool band = (cb - rb <= 1) && (rb - cb <= 1);

#pragma unroll
    for (int f = 0; f < 4; ++f) {
        int col_local = wx * 64 + f * 16 + i;
        int hw_c = cb * 128 + col_local;
        float v = Vs[col_local];
        int cimg_r = hw_c >> 5, cimg_c = hw_c & 31;
#pragma unroll
        for (int r = 0; r < 4; ++r)
#pragma unroll
            for (int g = 0; g < 4; ++g) {
                float e = __expf(acc[r][f][g]);
                st[r][g]  += e;
                stv[r][g] += e * v;
                if (band) {
                    int row_local = wy * 64 + r * 16 + q * 4 + g;
                    int hw_r = rb * 128 + row_local;
                    int dy = cimg_r - (hw_r >> 5);
                    int dx = cimg_c - (hw_r & 31);
                    if ((unsigned)(dy + 2) <= 4u && (unsigned)(dx + 2) <= 4u)
                        D[(size_t)(b * HW_N + hw_r) * 25 + (dy + 2) * 5 + (dx + 2)] = e;
                }
            }
    }

    // ---- block reduction (scratch aliases staging LDS) -> double partials ----
    __syncthreads();
    float* scrT  = (float*)lds;              // 128 x 33 fp32
    float* scrTV = (float*)(lds + SCR2);
#pragma unroll
    for (int r = 0; r < 4; ++r)
#pragma unroll
        for (int g = 0; g < 4; ++g) {
            int rl = wy * 64 + r * 16 + q * 4 + g;
            scrT [rl * 33 + wx * 16 + i] = st[r][g];
            scrTV[rl * 33 + wx * 16 + i] = stv[r][g];
        }
    __syncthreads();
    if (t < 128) {
        double s = 0.0;
#pragma unroll
        for (int c = 0; c < 32; ++c) s += (double)scrT[t * 33 + c];
        Tp[(size_t)(b * HW_N + rb * 128 + t) * 8 + cb] = s;
    } else {
        int tt = t - 128;
        double s = 0.0;
#pragma unroll
        for (int c = 0; c < 32; ++c) s += (double)scrTV[tt * 33 + c];
        TVp[(size_t)(b * HW_N + rb * 128 + tt) * 8 + cb] = s;
    }
}

// -------------------------------------------------------------------------
// Kernel C: sum partials -> T,TV; gates; out = sum_p gate_p * xf rows.
// grid (30, 8) x 256 threads.
// -------------------------------------------------------------------------
__global__ __launch_bounds__(256) void gate_out_kernel(
    const float* __restrict__ xf, const float* __restrict__ V,
    const double* __restrict__ Tp, const double* __restrict__ TVp,
    const float* __restrict__ D, float* __restrict__ out)
{
    const int fi = blockIdx.x;   // 0..29
    const int b  = blockIdx.y;
    const int t  = threadIdx.x;

    __shared__ float  xs[96 * 128];   // 3 img rows x 32 cols x 128 ch
    __shared__ float  gates[30][9];
    __shared__ double Ts[96], TVs[96];

#pragma unroll
    for (int m = 0; m < 12; ++m) {
        int id   = t + 256 * m;
        int srow = id >> 5;
        int c4   = id & 31;
        int r3   = srow >> 5, colc = srow & 31;
        *(float4*)&xs[srow * 128 + c4 * 4] =
            *(const float4*)&xf[((size_t)(b * 32 + fi + r3) * 32 + colc) * CD + c4 * 4];
    }

    if (t < 96) {
        int R = b * HW_N + (fi + (t >> 5)) * W_IMG + (t & 31);
        double s = 0.0;
#pragma unroll
        for (int c = 0; c < 8; ++c) s += Tp[(size_t)R * 8 + c];
        Ts[t] = s;
    } else if (t >= 128 && t < 224) {
        int tt = t - 128;
        int R = b * HW_N + (fi + (tt >> 5)) * W_IMG + (tt & 31);
        double s = 0.0;
#pragma unroll
        for (int c = 0; c < 8; ++c) s += TVp[(size_t)R * 8 + c];
        TVs[tt] = s;
    }
    __syncthreads();

    for (int g = t; g < 270; g += 256) {
        int fj = g / 9, p = g % 9;
        int pr = p / 3, pc = p % 3;
        int lrow = pr * 32 + fj + pc;
        int ip = (fi + pr) * W_IMG + (fj + pc);
        const float* Drow = &D[(size_t)(b * HW_N + ip) * 25];
        double se = 0.0, sev = 0.0;
#pragma unroll
        for (int qq = 0; qq < 9; ++qq) {
            int qr = qq / 3, qc = qq % 3;
            float e = Drow[(qr - pr + 2) * 5 + (qc - pc + 2)];
            se  += (double)e;
            sev += (double)(e * V[b * HW_N + (fi + qr) * W_IMG + (fj + qc)]);
        }
        double denom = Ts[lrow] - se + 1e-5;
        double numer = TVs[lrow] - sev;
        gates[fj][p] = (float)(numer / denom);
    }
    __syncthreads();

    const int c   = t & 127;
    const int fjg = t >> 7;
#pragma unroll
    for (int it = 0; it < 15; ++it) {
        int fj = fjg * 15 + it;
        float o = 0.f;
#pragma unroll
        for (int p = 0; p < 9; ++p) {
            int pr = p / 3, pc = p % 3;
            o += gates[fj][p] * xs[(pr * 32 + fj + pc) * 128 + c];
        }
        out[((size_t)(b * F_N) + fi * CH_O + fj) * CD + c] = o;
    }
}

// -------------------------------------------------------------------------
extern "C" void kernel_launch(void* const* d_in, const int* in_sizes, int n_in,
                              void* d_out, int out_size, void* d_ws, size_t ws_size,
                              hipStream_t stream)
{
    (void)in_sizes; (void)n_in; (void)out_size; (void)ws_size;
    const float* batch = (const float*)d_in[0];
    const float* Wq    = (const float*)d_in[1];
    const float* bq    = (const float*)d_in[2];
    const float* Wk    = (const float*)d_in[3];
    const float* bk    = (const float*)d_in[4];
    const float* wv    = (const float*)d_in[5];
    const float* bv    = (const float*)d_in[6];

    char*    ws  = (char*)d_ws;
    __bf16*  Qh  = (__bf16*)(ws + OFF_QH);
    __bf16*  Ql  = (__bf16*)(ws + OFF_QL);
    __bf16*  Kh  = (__bf16*)(ws + OFF_KH);
    __bf16*  Kl  = (__bf16*)(ws + OFF_KL);
    float*   V   = (float*)(ws + OFF_V);
    float*   D   = (float*)(ws + OFF_D);
    double*  Tp  = (double*)(ws + OFF_TP);
    double*  TVp = (double*)(ws + OFF_TVP);
    float*   out = (float*)d_out;

    qkv_kernel<<<dim3(256), dim3(256), 0, stream>>>(batch, Wq, bq, Wk, bk, wv, bv,
                                                    Qh, Ql, Kh, Kl, V);
    attn_kernel<<<dim3(8, 8, 8), dim3(256), ATTN_LDS_TOTAL, stream>>>(
        Qh, Ql, Kh, Kl, V, Tp, TVp, D);
    gate_out_kernel<<<dim3(CH_O, BATCH), dim3(256), 0, stream>>>(batch, V, Tp, TVp, D, out);
}

// Round 4
// 102.680 us; speedup vs baseline: 1.1596x; 1.1596x over previous
//
#include <hip/hip_runtime.h>

// Problem constants
#define BATCH 8
#define HW_N  1024   // 32*32
#define CD    128    // channels
#define W_IMG 32
#define CH_O  30
#define F_N   900    // 30*30

// Workspace layout (bytes)
#define OFF_QH  0u
#define OFF_QL  2097152u
#define OFF_KH  4194304u
#define OFF_KL  6291456u
#define OFF_V   8388608u
#define OFF_D   8421376u    // 8192*25*4 = 819200
#define OFF_TP  9240576u    // 8192*8 doubles = 524288
#define OFF_TVP 9764864u    // -> ends 10289152
#define OFF_WQH 10289152u   // 4 x 32768 B packed weight splits
#define OFF_WQL 10321920u
#define OFF_WKH 10354688u
#define OFF_WKL 10387456u   // ends 10420224

typedef __bf16 bf16x8 __attribute__((ext_vector_type(8)));
typedef __bf16 bf16x4 __attribute__((ext_vector_type(4)));
typedef float  f32x4  __attribute__((ext_vector_type(4)));

// MFMA-fragment-order layout (A-operand order for row-major [R][k]):
// off(R,k) = (R>>4)*2048 + [ (k>>5)*4 + ((k>>3)&3) ]*128 + (R&15)*8 + (k&7)
__device__ __forceinline__ size_t frag_off(int R, int k) {
    return (size_t)(R >> 4) * 2048 +
           (size_t)((((k >> 5) * 4 + ((k >> 3) & 3)) * 128) + ((R & 15) * 8) + (k & 7));
}

__device__ __forceinline__ void async16(const __bf16* g, __bf16* l) {
    __builtin_amdgcn_global_load_lds(
        (const __attribute__((address_space(1))) unsigned int*)g,
        (__attribute__((address_space(3))) unsigned int*)l,
        16, 0, 0);
}

// -------------------------------------------------------------------------
// Kernel P: pack Wq, Wk (fp32 row-major) into bf16-split frag-order arrays.
// grid 8 x 256; thread -> (channel c, 8-wide k chunk) of both matrices.
// -------------------------------------------------------------------------
__global__ __launch_bounds__(256) void prep_kernel(
    const float* __restrict__ Wq, const float* __restrict__ Wk,
    __bf16* __restrict__ WqhF, __bf16* __restrict__ WqlF,
    __bf16* __restrict__ WkhF, __bf16* __restrict__ WklF)
{
    int id = blockIdx.x * 256 + threadIdx.x;   // 0..2047
    int c  = id >> 4;
    int kc = id & 15;                          // 8-wide chunk
    size_t src = (size_t)c * CD + kc * 8;
    size_t dst = frag_off(c, kc * 8);

    float vq[8], vk[8];
    *(float4*)&vq[0] = *(const float4*)&Wq[src];
    *(float4*)&vq[4] = *(const float4*)&Wq[src + 4];
    *(float4*)&vk[0] = *(const float4*)&Wk[src];
    *(float4*)&vk[4] = *(const float4*)&Wk[src + 4];

    bf16x8 qh, ql, kh, kl;
#pragma unroll
    for (int e = 0; e < 8; ++e) {
        __bf16 h = (__bf16)vq[e];
        qh[e] = h; ql[e] = (__bf16)(vq[e] - (float)h);
        __bf16 h2 = (__bf16)vk[e];
        kh[e] = h2; kl[e] = (__bf16)(vk[e] - (float)h2);
    }
    *(bf16x8*)&WqhF[dst] = qh;
    *(bf16x8*)&WqlF[dst] = ql;
    *(bf16x8*)&WkhF[dst] = kh;
    *(bf16x8*)&WklF[dst] = kl;
}

// -------------------------------------------------------------------------
// Kernel A: Q/K via bf16 MFMA 3-term split; V fp32. 512 blocks x 16 rows.
// xf staged in LDS (fp32 for V + bf16 splits in A-frag order); weight
// B-frags read directly from global (L2-resident, frag-order, coalesced).
// -------------------------------------------------------------------------
__global__ __launch_bounds__(256) void qkv_kernel(
    const float* __restrict__ xf,
    const float* __restrict__ bq, const float* __restrict__ bk,
    const float* __restrict__ wv, const float* __restrict__ bv,
    const __bf16* __restrict__ WqhF, const __bf16* __restrict__ WqlF,
    const __bf16* __restrict__ WkhF, const __bf16* __restrict__ WklF,
    __bf16* __restrict__ Qh, __bf16* __restrict__ Ql,
    __bf16* __restrict__ Kh, __bf16* __restrict__ Kl,
    float* __restrict__ V)
{
    __shared__ float  xs[16][132];
    __shared__ __bf16 xh[2048];
    __shared__ __bf16 xl[2048];

    const int t = threadIdx.x;
    const int rowbase = blockIdx.x * 16;

    // stage 16x128 fp32 rows + bf16 splits (A-frag order)
#pragma unroll
    for (int m = 0; m < 2; ++m) {
        int id = t + 256 * m;          // 0..511 float4 chunks
        int r  = id >> 5;
        int c4 = id & 31;
        float4 v4 = *(const float4*)&xf[(size_t)(rowbase + r) * CD + c4 * 4];
        *(float4*)&xs[r][c4 * 4] = v4;
        int c = c4 * 4;
        int off = ((c >> 5) * 4 + ((c >> 3) & 3)) * 128 + r * 8 + (c & 7);
        float vv[4] = {v4.x, v4.y, v4.z, v4.w};
        bf16x4 hh, ll;
#pragma unroll
        for (int e = 0; e < 4; ++e) {
            __bf16 h = (__bf16)vv[e];
            hh[e] = h; ll[e] = (__bf16)(vv[e] - (float)h);
        }
        *(bf16x4*)&xh[off] = hh;
        *(bf16x4*)&xl[off] = ll;
    }
    __syncthreads();

    const int w    = t >> 6;
    const int lane = t & 63;
    const int q    = lane >> 4;
    const int i    = lane & 15;

    f32x4 aq[2], ak[2];
#pragma unroll
    for (int ct = 0; ct < 2; ++ct) {
        aq[ct] = (f32x4){0.f, 0.f, 0.f, 0.f};
        ak[ct] = (f32x4){0.f, 0.f, 0.f, 0.f};
    }

#pragma unroll
    for (int ks = 0; ks < 4; ++ks) {
        const int aoff = (ks * 4 + q) * 128 + i * 8;
        bf16x8 ah = *(bf16x8*)&xh[aoff];
        bf16x8 al = *(bf16x8*)&xl[aoff];
#pragma unroll
        for (int ct = 0; ct < 2; ++ct) {
            size_t boff = (size_t)(w * 2 + ct) * 2048 + (size_t)(ks * 4 + q) * 128 + i * 8;
            bf16x8 bqh = *(const bf16x8*)&WqhF[boff];
            bf16x8 bql = *(const bf16x8*)&WqlF[boff];
            bf16x8 bkh = *(const bf16x8*)&WkhF[boff];
            bf16x8 bkl = *(const bf16x8*)&WklF[boff];
            aq[ct] = __builtin_amdgcn_mfma_f32_16x16x32_bf16(ah, bqh, aq[ct], 0, 0, 0);
            aq[ct] = __builtin_amdgcn_mfma_f32_16x16x32_bf16(ah, bql, aq[ct], 0, 0, 0);
            aq[ct] = __builtin_amdgcn_mfma_f32_16x16x32_bf16(al, bqh, aq[ct], 0, 0, 0);
            ak[ct] = __builtin_amdgcn_mfma_f32_16x16x32_bf16(ah, bkh, ak[ct], 0, 0, 0);
            ak[ct] = __builtin_amdgcn_mfma_f32_16x16x32_bf16(ah, bkl, ak[ct], 0, 0, 0);
            ak[ct] = __builtin_amdgcn_mfma_f32_16x16x32_bf16(al, bkh, ak[ct], 0, 0, 0);
        }
    }

    // epilogue: bias, split, frag-order store
#pragma unroll
    for (int ct = 0; ct < 2; ++ct) {
        int c = (w * 2 + ct) * 16 + i;
        float bqv = bq[c], bkv = bk[c];
#pragma unroll
        for (int g = 0; g < 4; ++g) {
            int R = rowbase + q * 4 + g;
            size_t o = frag_off(R, c);   // note: (R,c) with c as "k" inner dim
            float qv = aq[ct][g] + bqv;
            float kv = ak[ct][g] + bkv;
            __bf16 h = (__bf16)qv;
            Qh[o] = h; Ql[o] = (__bf16)(qv - (float)h);
            __bf16 h2 = (__bf16)kv;
            Kh[o] = h2; Kl[o] = (__bf16)(kv - (float)h2);
        }
    }

    if (t < 16) {
        float s = 0.f;
#pragma unroll 8
        for (int k = 0; k < CD; ++k) s += xs[t][k] * wv[k];
        V[rowbase + t] = s + bv[0];
    }
}

// -------------------------------------------------------------------------
// Kernel B: S = Q@K^T (bf16 MFMA, 3-term split), fused exp/rowsums/band.
// grid (8,8,8); 256 thr = 4 waves 2x2; global_load_lds staging; partials.
// -------------------------------------------------------------------------
#define A_H 0
#define A_L 16384
#define B_H 32768
#define B_L 49152
#define VS_OFF 65536
#define ATTN_LDS_TOTAL 66048
#define SCR2 16896

__global__ __launch_bounds__(256, 2) void attn_kernel(
    const __bf16* __restrict__ Qh, const __bf16* __restrict__ Ql,
    const __bf16* __restrict__ Kh, const __bf16* __restrict__ Kl,
    const float* __restrict__ V,
    double* __restrict__ Tp, double* __restrict__ TVp,
    float* __restrict__ D)
{
    extern __shared__ char lds[];
    __bf16* Ah = (__bf16*)(lds + A_H);
    __bf16* Al = (__bf16*)(lds + A_L);
    __bf16* Bh = (__bf16*)(lds + B_H);
    __bf16* Bl = (__bf16*)(lds + B_L);
    float*  Vs = (float*)(lds + VS_OFF);

    const int b  = blockIdx.x;
    const int rb = blockIdx.y;
    const int cb = blockIdx.z;
    const int t  = threadIdx.x;
    const int w    = t >> 6;
    const int lane = t & 63;
    const int q    = lane >> 4;
    const int i    = lane & 15;
    const int wy = w >> 1, wx = w & 1;

    if (t < 128) Vs[t] = V[b * HW_N + cb * 128 + t];

    f32x4 acc[4][4];
#pragma unroll
    for (int r = 0; r < 4; ++r)
#pragma unroll
        for (int f = 0; f < 4; ++f) acc[r][f] = (f32x4){0.f, 0.f, 0.f, 0.f};

    const size_t abase = (size_t)(b * 8 + rb) * 16384;   // bf16 units
    const size_t bbase = (size_t)(b * 8 + cb) * 16384;

    for (int kh = 0; kh < 2; ++kh) {
        __syncthreads();
#pragma unroll
        for (int m = 0; m < 4; ++m) {
            int id = t + 256 * m;                    // 0..1023, 16B chunks
            size_t goff = (size_t)(id >> 7) * 2048 + kh * 1024 + (id & 127) * 8;
            int loff = id * 8;                       // identity LDS layout
            async16(Qh + abase + goff, Ah + loff);
            async16(Ql + abase + goff, Al + loff);
            async16(Kh + bbase + goff, Bh + loff);
            async16(Kl + bbase + goff, Bl + loff);
        }
        asm volatile("s_waitcnt vmcnt(0)" ::: "memory");
        __syncthreads();

#pragma unroll
        for (int kcl = 0; kcl < 2; ++kcl) {
            bf16x8 ah[4], al4[4], bh4[4], bl4[4];
#pragma unroll
            for (int r = 0; r < 4; ++r) {
                int ao = (((wy * 4 + r) * 2 + kcl) * 4 + q) * 128 + i * 8;
                ah[r]  = *(bf16x8*)&Ah[ao];
                al4[r] = *(bf16x8*)&Al[ao];
                int bo = (((wx * 4 + r) * 2 + kcl) * 4 + q) * 128 + i * 8;
                bh4[r] = *(bf16x8*)&Bh[bo];
                bl4[r] = *(bf16x8*)&Bl[bo];
            }
#pragma unroll
            for (int r = 0; r < 4; ++r)
#pragma unroll
                for (int f = 0; f < 4; ++f) {
                    acc[r][f] = __builtin_amdgcn_mfma_f32_16x16x32_bf16(
                        ah[r], bh4[f], acc[r][f], 0, 0, 0);
                    acc[r][f] = __builtin_amdgcn_mfma_f32_16x16x32_bf16(
                        ah[r], bl4[f], acc[r][f], 0, 0, 0);
                    acc[r][f] = __builtin_amdgcn_mfma_f32_16x16x32_bf16(
                        al4[r], bh4[f], acc[r][f], 0, 0, 0);
                }
        }
    }

    // ---- epilogue: exp, partial row sums, banded D store ----
    float st[4][4], stv[4][4];
#pragma unroll
    for (int r = 0; r < 4; ++r)
#pragma unroll
        for (int g = 0; g < 4; ++g) { st[r][g] = 0.f; stv[r][g] = 0.f; }

    const bool band = (cb - rb <= 1) && (rb - cb <= 1);

#pragma unroll
    for (int f = 0; f < 4; ++f) {
        int col_local = wx * 64 + f * 16 + i;
        int hw_c = cb * 128 + col_local;
        float v = Vs[col_local];
        int cimg_r = hw_c >> 5, cimg_c = hw_c & 31;
#pragma unroll
        for (int r = 0; r < 4; ++r)
#pragma unroll
            for (int g = 0; g < 4; ++g) {
                float e = __expf(acc[r][f][g]);
                st[r][g]  += e;
                stv[r][g] += e * v;
                if (band) {
                    int row_local = wy * 64 + r * 16 + q * 4 + g;
                    int hw_r = rb * 128 + row_local;
                    int dy = cimg_r - (hw_r >> 5);
                    int dx = cimg_c - (hw_r & 31);
                    if ((unsigned)(dy + 2) <= 4u && (unsigned)(dx + 2) <= 4u)
                        D[(size_t)(b * HW_N + hw_r) * 25 + (dy + 2) * 5 + (dx + 2)] = e;
                }
            }
    }

    // ---- block reduction (scratch aliases staging LDS) -> double partials ----
    __syncthreads();
    float* scrT  = (float*)lds;              // 128 x 33 fp32
    float* scrTV = (float*)(lds + SCR2);
#pragma unroll
    for (int r = 0; r < 4; ++r)
#pragma unroll
        for (int g = 0; g < 4; ++g) {
            int rl = wy * 64 + r * 16 + q * 4 + g;
            scrT [rl * 33 + wx * 16 + i] = st[r][g];
            scrTV[rl * 33 + wx * 16 + i] = stv[r][g];
        }
    __syncthreads();
    if (t < 128) {
        double s = 0.0;
#pragma unroll
        for (int c = 0; c < 32; ++c) s += (double)scrT[t * 33 + c];
        Tp[(size_t)(b * HW_N + rb * 128 + t) * 8 + cb] = s;
    } else {
        int tt = t - 128;
        double s = 0.0;
#pragma unroll
        for (int c = 0; c < 32; ++c) s += (double)scrTV[tt * 33 + c];
        TVp[(size_t)(b * HW_N + rb * 128 + tt) * 8 + cb] = s;
    }
}

// -------------------------------------------------------------------------
// Kernel C: sum partials -> T,TV; gates; out = sum_p gate_p * xf rows.
// grid (30, 8) x 256 threads.
// -------------------------------------------------------------------------
__global__ __launch_bounds__(256) void gate_out_kernel(
    const float* __restrict__ xf, const float* __restrict__ V,
    const double* __restrict__ Tp, const double* __restrict__ TVp,
    const float* __restrict__ D, float* __restrict__ out)
{
    const int fi = blockIdx.x;   // 0..29
    const int b  = blockIdx.y;
    const int t  = threadIdx.x;

    __shared__ float  xs[96 * 128];   // 3 img rows x 32 cols x 128 ch
    __shared__ float  gates[30][9];
    __shared__ double Ts[96], TVs[96];

#pragma unroll
    for (int m = 0; m < 12; ++m) {
        int id   = t + 256 * m;
        int srow = id >> 5;
        int c4   = id & 31;
        int r3   = srow >> 5, colc = srow & 31;
        *(float4*)&xs[srow * 128 + c4 * 4] =
            *(const float4*)&xf[((size_t)(b * 32 + fi + r3) * 32 + colc) * CD + c4 * 4];
    }

    if (t < 96) {
        int R = b * HW_N + (fi + (t >> 5)) * W_IMG + (t & 31);
        double s = 0.0;
#pragma unroll
        for (int c = 0; c < 8; ++c) s += Tp[(size_t)R * 8 + c];
        Ts[t] = s;
    } else if (t >= 128 && t < 224) {
        int tt = t - 128;
        int R = b * HW_N + (fi + (tt >> 5)) * W_IMG + (tt & 31);
        double s = 0.0;
#pragma unroll
        for (int c = 0; c < 8; ++c) s += TVp[(size_t)R * 8 + c];
        TVs[tt] = s;
    }
    __syncthreads();

    for (int g = t; g < 270; g += 256) {
        int fj = g / 9, p = g % 9;
        int pr = p / 3, pc = p % 3;
        int lrow = pr * 32 + fj + pc;
        int ip = (fi + pr) * W_IMG + (fj + pc);
        const float* Drow = &D[(size_t)(b * HW_N + ip) * 25];
        double se = 0.0, sev = 0.0;
#pragma unroll
        for (int qq = 0; qq < 9; ++qq) {
            int qr = qq / 3, qc = qq % 3;
            float e = Drow[(qr - pr + 2) * 5 + (qc - pc + 2)];
            se  += (double)e;
            sev += (double)(e * V[b * HW_N + (fi + qr) * W_IMG + (fj + qc)]);
        }
        double denom = Ts[lrow] - se + 1e-5;
        double numer = TVs[lrow] - sev;
        gates[fj][p] = (float)(numer / denom);
    }
    __syncthreads();

    const int c   = t & 127;
    const int fjg = t >> 7;
#pragma unroll
    for (int it = 0; it < 15; ++it) {
        int fj = fjg * 15 + it;
        float o = 0.f;
#pragma unroll
        for (int p = 0; p < 9; ++p) {
            int pr = p / 3, pc = p % 3;
            o += gates[fj][p] * xs[(pr * 32 + fj + pc) * 128 + c];
        }
        out[((size_t)(b * F_N) + fi * CH_O + fj) * CD + c] = o;
    }
}

// -------------------------------------------------------------------------
extern "C" void kernel_launch(void* const* d_in, const int* in_sizes, int n_in,
                              void* d_out, int out_size, void* d_ws, size_t ws_size,
                              hipStream_t stream)
{
    (void)in_sizes; (void)n_in; (void)out_size; (void)ws_size;
    const float* batch = (const float*)d_in[0];
    const float* Wq    = (const float*)d_in[1];
    const float* bq    = (const float*)d_in[2];
    const float* Wk    = (const float*)d_in[3];
    const float* bk    = (const float*)d_in[4];
    const float* wv    = (const float*)d_in[5];
    const float* bv    = (const float*)d_in[6];

    char*    ws  = (char*)d_ws;
    __bf16*  Qh  = (__bf16*)(ws + OFF_QH);
    __bf16*  Ql  = (__bf16*)(ws + OFF_QL);
    __bf16*  Kh  = (__bf16*)(ws + OFF_KH);
    __bf16*  Kl  = (__bf16*)(ws + OFF_KL);
    float*   V   = (float*)(ws + OFF_V);
    float*   D   = (float*)(ws + OFF_D);
    double*  Tp  = (double*)(ws + OFF_TP);
    double*  TVp = (double*)(ws + OFF_TVP);
    __bf16*  WqhF = (__bf16*)(ws + OFF_WQH);
    __bf16*  WqlF = (__bf16*)(ws + OFF_WQL);
    __bf16*  WkhF = (__bf16*)(ws + OFF_WKH);
    __bf16*  WklF = (__bf16*)(ws + OFF_WKL);
    float*   out = (float*)d_out;

    prep_kernel<<<dim3(8), dim3(256), 0, stream>>>(Wq, Wk, WqhF, WqlF, WkhF, WklF);
    qkv_kernel<<<dim3(512), dim3(256), 0, stream>>>(batch, bq, bk, wv, bv,
                                                    WqhF, WqlF, WkhF, WklF,
                                                    Qh, Ql, Kh, Kl, V);
    attn_kernel<<<dim3(8, 8, 8), dim3(256), ATTN_LDS_TOTAL, stream>>>(
        Qh, Ql, Kh, Kl, V, Tp, TVp, D);
    gate_out_kernel<<<dim3(CH_O, BATCH), dim3(256), 0, stream>>>(batch, V, Tp, TVp, D, out);
}

// Round 5
// 98.454 us; speedup vs baseline: 1.2094x; 1.0429x over previous
//
#include <hip/hip_runtime.h>

// Problem constants
#define BATCH 8
#define HW_N  1024   // 32*32
#define CD    128    // channels
#define W_IMG 32
#define CH_O  30
#define F_N   900    // 30*30

// Workspace layout (bytes)
#define OFF_Q16 0u          // 8192*128*2 = 2 MB
#define OFF_K16 2097152u
#define OFF_V   4194304u    // 32 KB
#define OFF_D   4227072u    // 8192*25*4 = 819200
#define OFF_TP  5046272u    // 8192*8 doubles
#define OFF_TVP 5570560u
#define OFF_WQH 6094848u    // 4 x 32768 B fp16 weight splits
#define OFF_WQL 6127616u
#define OFF_WKH 6160384u
#define OFF_WKL 6193152u    // ends 6225920

typedef _Float16 f16x8 __attribute__((ext_vector_type(8)));
typedef _Float16 f16x4 __attribute__((ext_vector_type(4)));
typedef float    f32x4 __attribute__((ext_vector_type(4)));

// MFMA-fragment-order layout for row-major [R][k]:
// off(R,k) = (R>>4)*2048 + [ (k>>5)*4 + ((k>>3)&3) ]*128 + (R&15)*8 + (k&7)
__device__ __forceinline__ size_t frag_off(int R, int k) {
    return (size_t)(R >> 4) * 2048 +
           (size_t)((((k >> 5) * 4 + ((k >> 3) & 3)) * 128) + ((R & 15) * 8) + (k & 7));
}

__device__ __forceinline__ void async16(const void* g, void* l) {
    __builtin_amdgcn_global_load_lds(
        (const __attribute__((address_space(1))) unsigned int*)g,
        (__attribute__((address_space(3))) unsigned int*)l,
        16, 0, 0);
}

// -------------------------------------------------------------------------
// Kernel P: pack Wq, Wk (fp32) into fp16-split frag-order arrays.
// grid 8 x 256; thread -> (channel c, 8-wide k chunk).
// -------------------------------------------------------------------------
__global__ __launch_bounds__(256) void prep_kernel(
    const float* __restrict__ Wq, const float* __restrict__ Wk,
    _Float16* __restrict__ WqH, _Float16* __restrict__ WqL,
    _Float16* __restrict__ WkH, _Float16* __restrict__ WkL)
{
    int id = blockIdx.x * 256 + threadIdx.x;   // 0..2047
    int c  = id >> 4;
    int kc = id & 15;
    size_t src = (size_t)c * CD + kc * 8;
    size_t dst = frag_off(c, kc * 8);

    float vq[8], vk[8];
    *(float4*)&vq[0] = *(const float4*)&Wq[src];
    *(float4*)&vq[4] = *(const float4*)&Wq[src + 4];
    *(float4*)&vk[0] = *(const float4*)&Wk[src];
    *(float4*)&vk[4] = *(const float4*)&Wk[src + 4];

    f16x8 qh, ql, kh, kl;
#pragma unroll
    for (int e = 0; e < 8; ++e) {
        _Float16 h = (_Float16)vq[e];
        qh[e] = h; ql[e] = (_Float16)(vq[e] - (float)h);
        _Float16 h2 = (_Float16)vk[e];
        kh[e] = h2; kl[e] = (_Float16)(vk[e] - (float)h2);
    }
    *(f16x8*)&WqH[dst] = qh;
    *(f16x8*)&WqL[dst] = ql;
    *(f16x8*)&WkH[dst] = kh;
    *(f16x8*)&WkL[dst] = kl;
}

// -------------------------------------------------------------------------
// Kernel A: Q/K via fp16 MFMA 3-term split (near-exact); V fp32.
// 512 blocks x 16 rows. Outputs SINGLE-fp16 Q16/K16 in frag order.
// -------------------------------------------------------------------------
__global__ __launch_bounds__(256) void qkv_kernel(
    const float* __restrict__ xf,
    const float* __restrict__ bq, const float* __restrict__ bk,
    const float* __restrict__ wv, const float* __restrict__ bv,
    const _Float16* __restrict__ WqH, const _Float16* __restrict__ WqL,
    const _Float16* __restrict__ WkH, const _Float16* __restrict__ WkL,
    _Float16* __restrict__ Q16, _Float16* __restrict__ K16,
    float* __restrict__ V)
{
    __shared__ float    xs[16][132];
    __shared__ _Float16 xh[2048];
    __shared__ _Float16 xl[2048];

    const int t = threadIdx.x;
    const int rowbase = blockIdx.x * 16;

#pragma unroll
    for (int m = 0; m < 2; ++m) {
        int id = t + 256 * m;          // 0..511 float4 chunks
        int r  = id >> 5;
        int c4 = id & 31;
        float4 v4 = *(const float4*)&xf[(size_t)(rowbase + r) * CD + c4 * 4];
        *(float4*)&xs[r][c4 * 4] = v4;
        int c = c4 * 4;
        int off = ((c >> 5) * 4 + ((c >> 3) & 3)) * 128 + r * 8 + (c & 7);
        float vv[4] = {v4.x, v4.y, v4.z, v4.w};
        f16x4 hh, ll;
#pragma unroll
        for (int e = 0; e < 4; ++e) {
            _Float16 h = (_Float16)vv[e];
            hh[e] = h; ll[e] = (_Float16)(vv[e] - (float)h);
        }
        *(f16x4*)&xh[off] = hh;
        *(f16x4*)&xl[off] = ll;
    }
    __syncthreads();

    const int w    = t >> 6;
    const int lane = t & 63;
    const int q    = lane >> 4;
    const int i    = lane & 15;

    f32x4 aq[2], ak[2];
#pragma unroll
    for (int ct = 0; ct < 2; ++ct) {
        aq[ct] = (f32x4){0.f, 0.f, 0.f, 0.f};
        ak[ct] = (f32x4){0.f, 0.f, 0.f, 0.f};
    }

#pragma unroll
    for (int ks = 0; ks < 4; ++ks) {
        const int aoff = (ks * 4 + q) * 128 + i * 8;
        f16x8 ah = *(f16x8*)&xh[aoff];
        f16x8 al = *(f16x8*)&xl[aoff];
#pragma unroll
        for (int ct = 0; ct < 2; ++ct) {
            size_t boff = (size_t)(w * 2 + ct) * 2048 + (size_t)(ks * 4 + q) * 128 + i * 8;
            f16x8 bqh = *(const f16x8*)&WqH[boff];
            f16x8 bql = *(const f16x8*)&WqL[boff];
            f16x8 bkh = *(const f16x8*)&WkH[boff];
            f16x8 bkl = *(const f16x8*)&WkL[boff];
            aq[ct] = __builtin_amdgcn_mfma_f32_16x16x32_f16(ah, bqh, aq[ct], 0, 0, 0);
            aq[ct] = __builtin_amdgcn_mfma_f32_16x16x32_f16(ah, bql, aq[ct], 0, 0, 0);
            aq[ct] = __builtin_amdgcn_mfma_f32_16x16x32_f16(al, bqh, aq[ct], 0, 0, 0);
            ak[ct] = __builtin_amdgcn_mfma_f32_16x16x32_f16(ah, bkh, ak[ct], 0, 0, 0);
            ak[ct] = __builtin_amdgcn_mfma_f32_16x16x32_f16(ah, bkl, ak[ct], 0, 0, 0);
            ak[ct] = __builtin_amdgcn_mfma_f32_16x16x32_f16(al, bkh, ak[ct], 0, 0, 0);
        }
    }

    // epilogue: bias, single-fp16 store in frag order
#pragma unroll
    for (int ct = 0; ct < 2; ++ct) {
        int c = (w * 2 + ct) * 16 + i;
        float bqv = bq[c], bkv = bk[c];
#pragma unroll
        for (int g = 0; g < 4; ++g) {
            int R = rowbase + q * 4 + g;
            size_t o = frag_off(R, c);
            Q16[o] = (_Float16)(aq[ct][g] + bqv);
            K16[o] = (_Float16)(ak[ct][g] + bkv);
        }
    }

    if (t < 16) {
        float s = 0.f;
#pragma unroll 8
        for (int k = 0; k < CD; ++k) s += xs[t][k] * wv[k];
        V[rowbase + t] = s + bv[0];
    }
}

// -------------------------------------------------------------------------
// Kernel B: S = Q@K^T, single fp16 MFMA term; fused exp/rowsums/band.
// grid (8,8,8); 256 thr = 4 waves 2x2; global_load_lds staging; partials.
// -------------------------------------------------------------------------
#define A_OFF 0
#define B_OFF 16384
#define VS_OFF 32768
#define SCR2 16896
#define ATTN_LDS_TOTAL 33792

__global__ __launch_bounds__(256) void attn_kernel(
    const _Float16* __restrict__ Q16, const _Float16* __restrict__ K16,
    const float* __restrict__ V,
    double* __restrict__ Tp, double* __restrict__ TVp,
    float* __restrict__ D)
{
    extern __shared__ char lds[];
    _Float16* Ah = (_Float16*)(lds + A_OFF);
    _Float16* Bh = (_Float16*)(lds + B_OFF);
    float*    Vs = (float*)(lds + VS_OFF);

    const int b  = blockIdx.x;
    const int rb = blockIdx.y;
    const int cb = blockIdx.z;
    const int t  = threadIdx.x;
    const int w    = t >> 6;
    const int lane = t & 63;
    const int q    = lane >> 4;
    const int i    = lane & 15;
    const int wy = w >> 1, wx = w & 1;

    if (t < 128) Vs[t] = V[b * HW_N + cb * 128 + t];

    f32x4 acc[4][4];
#pragma unroll
    for (int r = 0; r < 4; ++r)
#pragma unroll
        for (int f = 0; f < 4; ++f) acc[r][f] = (f32x4){0.f, 0.f, 0.f, 0.f};

    const size_t abase = (size_t)(b * 8 + rb) * 16384;   // fp16 units
    const size_t bbase = (size_t)(b * 8 + cb) * 16384;

    for (int kh = 0; kh < 2; ++kh) {
        __syncthreads();
#pragma unroll
        for (int m = 0; m < 4; ++m) {
            int id = t + 256 * m;                    // 0..1023, 16B chunks
            size_t goff = (size_t)(id >> 7) * 2048 + kh * 1024 + (id & 127) * 8;
            int loff = id * 8;                       // identity LDS layout
            async16(Q16 + abase + goff, Ah + loff);
            async16(K16 + bbase + goff, Bh + loff);
        }
        asm volatile("s_waitcnt vmcnt(0)" ::: "memory");
        __syncthreads();

#pragma unroll
        for (int kcl = 0; kcl < 2; ++kcl) {
            f16x8 a4[4], b4[4];
#pragma unroll
            for (int r = 0; r < 4; ++r) {
                int ao = (((wy * 4 + r) * 2 + kcl) * 4 + q) * 128 + i * 8;
                a4[r] = *(f16x8*)&Ah[ao];
                int bo = (((wx * 4 + r) * 2 + kcl) * 4 + q) * 128 + i * 8;
                b4[r] = *(f16x8*)&Bh[bo];
            }
#pragma unroll
            for (int r = 0; r < 4; ++r)
#pragma unroll
                for (int f = 0; f < 4; ++f)
                    acc[r][f] = __builtin_amdgcn_mfma_f32_16x16x32_f16(
                        a4[r], b4[f], acc[r][f], 0, 0, 0);
        }
    }

    // ---- epilogue: exp, partial row sums, banded D store ----
    float st[4][4], stv[4][4];
#pragma unroll
    for (int r = 0; r < 4; ++r)
#pragma unroll
        for (int g = 0; g < 4; ++g) { st[r][g] = 0.f; stv[r][g] = 0.f; }

    const bool band = (cb - rb <= 1) && (rb - cb <= 1);

#pragma unroll
    for (int f = 0; f < 4; ++f) {
        int col_local = wx * 64 + f * 16 + i;
        int hw_c = cb * 128 + col_local;
        float v = Vs[col_local];
        int cimg_r = hw_c >> 5, cimg_c = hw_c & 31;
#pragma unroll
        for (int r = 0; r < 4; ++r)
#pragma unroll
            for (int g = 0; g < 4; ++g) {
                float e = __expf(acc[r][f][g]);
                st[r][g]  += e;
                stv[r][g] += e * v;
                if (band) {
                    int row_local = wy * 64 + r * 16 + q * 4 + g;
                    int hw_r = rb * 128 + row_local;
                    int dy = cimg_r - (hw_r >> 5);
                    int dx = cimg_c - (hw_r & 31);
                    if ((unsigned)(dy + 2) <= 4u && (unsigned)(dx + 2) <= 4u)
                        D[(size_t)(b * HW_N + hw_r) * 25 + (dy + 2) * 5 + (dx + 2)] = e;
                }
            }
    }

    // ---- block reduction (scratch aliases staging LDS) -> double partials ----
    __syncthreads();
    float* scrT  = (float*)lds;              // 128 x 33 fp32
    float* scrTV = (float*)(lds + SCR2);
#pragma unroll
    for (int r = 0; r < 4; ++r)
#pragma unroll
        for (int g = 0; g < 4; ++g) {
            int rl = wy * 64 + r * 16 + q * 4 + g;
            scrT [rl * 33 + wx * 16 + i] = st[r][g];
            scrTV[rl * 33 + wx * 16 + i] = stv[r][g];
        }
    __syncthreads();
    if (t < 128) {
        double s = 0.0;
#pragma unroll
        for (int c = 0; c < 32; ++c) s += (double)scrT[t * 33 + c];
        Tp[(size_t)(b * HW_N + rb * 128 + t) * 8 + cb] = s;
    } else {
        int tt = t - 128;
        double s = 0.0;
#pragma unroll
        for (int c = 0; c < 32; ++c) s += (double)scrTV[tt * 33 + c];
        TVp[(size_t)(b * HW_N + rb * 128 + tt) * 8 + cb] = s;
    }
}

// -------------------------------------------------------------------------
// Kernel C: sum partials -> T,TV; gates; out = sum_p gate_p * xf rows.
// grid (30, 8) x 256 threads.
// -------------------------------------------------------------------------
__global__ __launch_bounds__(256) void gate_out_kernel(
    const float* __restrict__ xf, const float* __restrict__ V,
    const double* __restrict__ Tp, const double* __restrict__ TVp,
    const float* __restrict__ D, float* __restrict__ out)
{
    const int fi = blockIdx.x;   // 0..29
    const int b  = blockIdx.y;
    const int t  = threadIdx.x;

    __shared__ float  xs[96 * 128];   // 3 img rows x 32 cols x 128 ch
    __shared__ float  gates[30][9];
    __shared__ double Ts[96], TVs[96];

#pragma unroll
    for (int m = 0; m < 12; ++m) {
        int id   = t + 256 * m;
        int srow = id >> 5;
        int c4   = id & 31;
        int r3   = srow >> 5, colc = srow & 31;
        *(float4*)&xs[srow * 128 + c4 * 4] =
            *(const float4*)&xf[((size_t)(b * 32 + fi + r3) * 32 + colc) * CD + c4 * 4];
    }

    if (t < 96) {
        int R = b * HW_N + (fi + (t >> 5)) * W_IMG + (t & 31);
        double s = 0.0;
#pragma unroll
        for (int c = 0; c < 8; ++c) s += Tp[(size_t)R * 8 + c];
        Ts[t] = s;
    } else if (t >= 128 && t < 224) {
        int tt = t - 128;
        int R = b * HW_N + (fi + (tt >> 5)) * W_IMG + (tt & 31);
        double s = 0.0;
#pragma unroll
        for (int c = 0; c < 8; ++c) s += TVp[(size_t)R * 8 + c];
        TVs[tt] = s;
    }
    __syncthreads();

    for (int g = t; g < 270; g += 256) {
        int fj = g / 9, p = g % 9;
        int pr = p / 3, pc = p % 3;
        int lrow = pr * 32 + fj + pc;
        int ip = (fi + pr) * W_IMG + (fj + pc);
        const float* Drow = &D[(size_t)(b * HW_N + ip) * 25];
        double se = 0.0, sev = 0.0;
#pragma unroll
        for (int qq = 0; qq < 9; ++qq) {
            int qr = qq / 3, qc = qq % 3;
            float e = Drow[(qr - pr + 2) * 5 + (qc - pc + 2)];
            se  += (double)e;
            sev += (double)(e * V[b * HW_N + (fi + qr) * W_IMG + (fj + qc)]);
        }
        double denom = Ts[lrow] - se + 1e-5;
        double numer = TVs[lrow] - sev;
        gates[fj][p] = (float)(numer / denom);
    }
    __syncthreads();

    const int c   = t & 127;
    const int fjg = t >> 7;
#pragma unroll
    for (int it = 0; it < 15; ++it) {
        int fj = fjg * 15 + it;
        float o = 0.f;
#pragma unroll
        for (int p = 0; p < 9; ++p) {
            int pr = p / 3, pc = p % 3;
            o += gates[fj][p] * xs[(pr * 32 + fj + pc) * 128 + c];
        }
        out[((size_t)(b * F_N) + fi * CH_O + fj) * CD + c] = o;
    }
}

// -------------------------------------------------------------------------
extern "C" void kernel_launch(void* const* d_in, const int* in_sizes, int n_in,
                              void* d_out, int out_size, void* d_ws, size_t ws_size,
                              hipStream_t stream)
{
    (void)in_sizes; (void)n_in; (void)out_size; (void)ws_size;
    const float* batch = (const float*)d_in[0];
    const float* Wq    = (const float*)d_in[1];
    const float* bq    = (const float*)d_in[2];
    const float* Wk    = (const float*)d_in[3];
    const float* bk    = (const float*)d_in[4];
    const float* wv    = (const float*)d_in[5];
    const float* bv    = (const float*)d_in[6];

    char*      ws  = (char*)d_ws;
    _Float16*  Q16 = (_Float16*)(ws + OFF_Q16);
    _Float16*  K16 = (_Float16*)(ws + OFF_K16);
    float*     V   = (float*)(ws + OFF_V);
    float*     D   = (float*)(ws + OFF_D);
    double*    Tp  = (double*)(ws + OFF_TP);
    double*    TVp = (double*)(ws + OFF_TVP);
    _Float16*  WqH = (_Float16*)(ws + OFF_WQH);
    _Float16*  WqL = (_Float16*)(ws + OFF_WQL);
    _Float16*  WkH = (_Float16*)(ws + OFF_WKH);
    _Float16*  WkL = (_Float16*)(ws + OFF_WKL);
    float*     out = (float*)d_out;

    prep_kernel<<<dim3(8), dim3(256), 0, stream>>>(Wq, Wk, WqH, WqL, WkH, WkL);
    qkv_kernel<<<dim3(512), dim3(256), 0, stream>>>(batch, bq, bk, wv, bv,
                                                    WqH, WqL, WkH, WkL,
                                                    Q16, K16, V);
    attn_kernel<<<dim3(8, 8, 8), dim3(256), ATTN_LDS_TOTAL, stream>>>(
        Q16, K16, V, Tp, TVp, D);
    gate_out_kernel<<<dim3(CH_O, BATCH), dim3(256), 0, stream>>>(batch, V, Tp, TVp, D, out);
}